// Round 9
// baseline (137.399 us; speedup 1.0000x reference)
//
#include <hip/hip_runtime.h>
#include <hip/hip_bf16.h>

#define NB 32
#define IN_DIM 256
#define NT 512
#define NL 512
#define NCONN 256
#define LN_EPS 1e-3f
#define M_TOT (NB * NT)   // 16384 rows

typedef __attribute__((ext_vector_type(8))) short short8;
typedef __attribute__((ext_vector_type(4))) float f32x4;

__device__ __forceinline__ void async_copy16(void* lds_dst, const void* g_src) {
    __builtin_amdgcn_global_load_lds(
        (const __attribute__((address_space(1))) unsigned int*)g_src,
        (__attribute__((address_space(3))) unsigned int*)lds_dst, 16, 0, 0);
}

// ---------------------------------------------------------------------------
// x prep: Axt[b*512+t][k] = bf16(x[b][k][t])
// ---------------------------------------------------------------------------
__global__ __launch_bounds__(256) void xprep_transpose(
    const float* __restrict__ x, __hip_bfloat16* __restrict__ Axt)
{
    __shared__ float t[64][65];
    const int tilesPerB = (IN_DIM / 64) * (NT / 64);
    const int b  = blockIdx.x / tilesPerB;
    const int tl = blockIdx.x % tilesPerB;
    const int k0 = (tl / (NT / 64)) * 64;
    const int t0 = (tl % (NT / 64)) * 64;
    const int tid = threadIdx.x;
    const float* src = x + (size_t)b * IN_DIM * NT;
    for (int idx = tid; idx < 4096; idx += 256) {
        const int kk = idx >> 6, tt = idx & 63;
        t[kk][tt] = src[(size_t)(k0 + kk) * NT + t0 + tt];
    }
    __syncthreads();
    for (int idx = tid; idx < 4096; idx += 256) {
        const int tt = idx >> 6, kk = idx & 63;
        Axt[((size_t)b * NT + t0 + tt) * IN_DIM + k0 + kk] =
            __float2bfloat16(t[kk][tt]);
    }
}

__global__ void fill_ihb(const float* __restrict__ init_h,
                         __hip_bfloat16* __restrict__ ihb)
{
    const int l = threadIdx.x;
    ihb[l] = __float2bfloat16(init_h[l]);
}

// ---------------------------------------------------------------------------
// Kernel 1 (MFMA 16x16x32): P = Axt @ WfT^T (64 rows x 512 cols per block),
// p = cos(P+bf), LN over cols, write zbuf [M][512] bf16.
// ---------------------------------------------------------------------------
__global__ __launch_bounds__(512, 2) void k1_mfma_fourier_ln(
    const __hip_bfloat16* __restrict__ Axt,   // [M_TOT][256]
    const __hip_bfloat16* __restrict__ WfT,   // [512][256]
    const float* __restrict__ bf, const float* __restrict__ gamma,
    const float* __restrict__ beta,
    __hip_bfloat16* __restrict__ zb)
{
    constexpr int ABYTES = 64 * 128;          // 8 KB
    constexpr int BBYTES = 512 * 128;         // 64 KB
    constexpr int NBUFB  = ABYTES + BBYTES;
    __shared__ __align__(16) char lds[2 * NBUFB];     // 144 KB
    __shared__ float pS[64][8], pQ[64][8];
    __shared__ float mS[64], rS[64];

    const int tid  = threadIdx.x;
    const int wave = tid >> 6, lane = tid & 63;
    const int m0 = blockIdx.x * 64;

    f32x4 acc[4][4];
#pragma unroll
    for (int mi = 0; mi < 4; mi++)
#pragma unroll
        for (int ni = 0; ni < 4; ni++) acc[mi][ni] = f32x4{0.f, 0.f, 0.f, 0.f};

    const int rowq = tid >> 3;
    const int sswz = ((tid & 7) ^ (rowq & 7)) << 4;
    const char* Ab = (const char*)Axt;
    const char* Bb = (const char*)WfT;

    auto stage = [&](int buf, int kt) {
        const size_t kb = (size_t)kt * 128;
        char* base = lds + buf * NBUFB;
        async_copy16(base + tid * 16,
                     Ab + (size_t)(m0 + rowq) * 512 + kb + sswz);
#pragma unroll
        for (int j = 0; j < 8; j++) {
            const int row = j * 64 + rowq;
            async_copy16(base + ABYTES + (j * 512 + tid) * 16,
                         Bb + (size_t)row * 512 + kb + sswz);
        }
    };

    const int l15 = lane & 15, lq = lane >> 4, l7 = lane & 7;
    int kxB[2];
#pragma unroll
    for (int ks = 0; ks < 2; ks++) kxB[ks] = ((ks * 4 + lq) ^ l7) << 4;

    stage(0, 0);
    int cur = 0;
#pragma unroll 1
    for (int kt = 0; kt < 4; kt++) {
        __syncthreads();
        if (kt + 1 < 4) stage(cur ^ 1, kt + 1);
        const char* sA = lds + cur * NBUFB;
        const char* sB = sA + ABYTES;
#pragma unroll
        for (int ks = 0; ks < 2; ks++) {
            const int kx = kxB[ks];
            short8 a[4], b[4];
#pragma unroll
            for (int mi = 0; mi < 4; mi++)
                a[mi] = *(const short8*)(sA + (size_t)(mi * 16 + l15) * 128 + kx);
#pragma unroll
            for (int ni = 0; ni < 4; ni++)
                b[ni] = *(const short8*)(sB +
                    (size_t)(wave * 64 + ni * 16 + l15) * 128 + kx);
#pragma unroll
            for (int ni = 0; ni < 4; ni++)
#pragma unroll
                for (int mi = 0; mi < 4; mi++)
                    acc[mi][ni] = __builtin_amdgcn_mfma_f32_16x16x32_bf16(
                        a[mi], b[ni], acc[mi][ni], 0, 0, 0);
        }
        cur ^= 1;
    }

    int cg[4]; float bfc[4];
#pragma unroll
    for (int ni = 0; ni < 4; ni++) {
        cg[ni] = wave * 64 + ni * 16 + l15;
        bfc[ni] = bf[cg[ni]];
    }

#pragma unroll
    for (int mi = 0; mi < 4; mi++) {
#pragma unroll
        for (int r = 0; r < 4; r++) {
            float s = 0.f, q = 0.f;
#pragma unroll
            for (int ni = 0; ni < 4; ni++) {
                const float p = __cosf(acc[mi][ni][r] + bfc[ni]);
                s += p; q += p * p;
            }
#pragma unroll
            for (int off = 8; off >= 1; off >>= 1) {
                s += __shfl_xor(s, off);
                q += __shfl_xor(q, off);
            }
            if (l15 == 0) {
                const int row = mi * 16 + lq * 4 + r;
                pS[row][wave] = s;
                pQ[row][wave] = q;
            }
        }
    }
    __syncthreads();
    if (tid < 64) {
        float a = 0.f, qq = 0.f;
#pragma unroll
        for (int w = 0; w < 8; w++) { a += pS[tid][w]; qq += pQ[tid][w]; }
        const float mu = a * (1.0f / NL);
        const float var = qq * (1.0f / NL) - mu * mu;
        mS[tid] = mu;
        rS[tid] = rsqrtf(var + LN_EPS);
    }
    __syncthreads();

    float gm[4], bt[4];
#pragma unroll
    for (int ni = 0; ni < 4; ni++) { gm[ni] = gamma[cg[ni]]; bt[ni] = beta[cg[ni]]; }

#pragma unroll
    for (int mi = 0; mi < 4; mi++) {
#pragma unroll
        for (int r = 0; r < 4; r++) {
            const int row = mi * 16 + lq * 4 + r;
            const int m = m0 + row;
            const float mu = mS[row], rs = rS[row];
#pragma unroll
            for (int ni = 0; ni < 4; ni++) {
                const float p = __cosf(acc[mi][ni][r] + bfc[ni]);
                const float z = gm[ni] * (p - mu) * rs + bt[ni];
                zb[(size_t)m * 512 + cg[ni]] = __float2bfloat16(z);
            }
        }
    }
}

// ---------------------------------------------------------------------------
// Weight transpose+convert / conn convert
// ---------------------------------------------------------------------------
__global__ __launch_bounds__(256) void wconv_transpose(
    const float* __restrict__ src, __hip_bfloat16* __restrict__ dst,
    int K, int N, int lddst, int k_off)
{
    __shared__ float t[64][65];
    const int ntn = N >> 6;
    const int k0 = (blockIdx.x / ntn) << 6;
    const int n0 = (blockIdx.x % ntn) << 6;
    const int tid = threadIdx.x;
    for (int idx = tid; idx < 4096; idx += 256) {
        const int kk = idx >> 6, nn = idx & 63;
        t[kk][nn] = src[(size_t)(k0 + kk) * N + n0 + nn];
    }
    __syncthreads();
    for (int idx = tid; idx < 4096; idx += 256) {
        const int nn = idx >> 6, kk = idx & 63;
        dst[(size_t)(n0 + nn) * lddst + k_off + k0 + kk] = __float2bfloat16(t[kk][nn]);
    }
}

__global__ __launch_bounds__(256) void conv_bf16_vec(
    const float* __restrict__ src, __hip_bfloat16* __restrict__ dst, int n)
{
    const int e = (blockIdx.x * 256 + threadIdx.x) * 4;
    if (e < n) {
        const float4 v = *(const float4*)(src + e);
        dst[e + 0] = __float2bfloat16(v.x);
        dst[e + 1] = __float2bfloat16(v.y);
        dst[e + 2] = __float2bfloat16(v.z);
        dst[e + 3] = __float2bfloat16(v.w);
    }
}

// ---------------------------------------------------------------------------
// m97-style MFMA GEMM v2: 256x128 tile, BK=64, 4 waves, wave-tile 128x64
// (acc[8][4], 16x16x32 frags), SINGLE 48 KB LDS buffer, 2 barriers per kt
// -> 2 resident blocks/CU (VGPR-capped), cross-block phase overlap.
// EPI 0: ub[m][n] = bf16(acc + bc[n])                    (u-GEMM, KTOT=256)
// EPI 1: merged gates, B rows 0..511 = [Wi;Ri]^T, 512..1023 = [Wg;Rg]^T:
//        n<512 : iu = sigmoid(acc+bi)*u -> ub;  n>=512: f = sigmoid(acc+bg) -> fb
//        A stitched: K<512 from zbuf[m], K>=512 from zbuf[m-1] / ihb (t=0)
// ---------------------------------------------------------------------------
template<int KTOT, int EPI>
__global__ __launch_bounds__(256, 2) void gemm256(
    const __hip_bfloat16* __restrict__ A,
    const __hip_bfloat16* __restrict__ B,
    const __hip_bfloat16* __restrict__ ihb,
    const float* __restrict__ bi, const float* __restrict__ bg,
    const float* __restrict__ bc,
    __hip_bfloat16* __restrict__ fb, __hip_bfloat16* __restrict__ ub)
{
    constexpr int NTN = (EPI == 1) ? 8 : 4;   // N-tiles
    constexpr int TB  = KTOT / 64;            // K-steps
    constexpr int ABYTES = 256 * 64 * 2;      // 32 KB
    __shared__ __align__(16) char lds[ABYTES + 128 * 64 * 2];   // 48 KB

    const int tid  = threadIdx.x;
    const int wave = tid >> 6, lane = tid & 63;
    const int wm = wave >> 1, wn = wave & 1;  // wave-tile 128x64 in 2x2 grid
    // XCD swizzle, n-fastest within XCD (A-panel L2 reuse)
    constexpr int CPX = 64 * NTN / 8;
    const int d = blockIdx.x;
    const int L = (d & 7) * CPX + (d >> 3);
    const int m0 = (L / NTN) << 8;
    const int n0 = (L % NTN) << 7;

    f32x4 acc[8][4];
#pragma unroll
    for (int mi = 0; mi < 8; mi++)
#pragma unroll
        for (int ni = 0; ni < 4; ni++) acc[mi][ni] = f32x4{0.f, 0.f, 0.f, 0.f};

    auto stage = [&](int kt) {
        // A: 256 rows x 64 el = 2048 16B-chunks, 8 per thread
#pragma unroll
        for (int j = 0; j < 8; j++) {
            const int i = j * 256 + tid;
            const int r = i >> 3;
            const int sl = (i & 7) ^ (r & 7);
            const int ke = kt * 64 + sl * 8;
            const __hip_bfloat16* srcA;
            if constexpr (EPI == 1) {
                const int m = m0 + r;
                if (ke < 512) {
                    srcA = A + (size_t)m * 512 + ke;
                } else {
                    const int k2 = ke - 512;
                    srcA = ((m & (NT - 1)) == 0) ? (ihb + k2)
                                                 : (A + (size_t)(m - 1) * 512 + k2);
                }
            } else {
                srcA = A + (size_t)(m0 + r) * KTOT + ke;
            }
            async_copy16(lds + i * 16, srcA);
        }
        // B: 128 rows x 64 el = 1024 chunks, 4 per thread
#pragma unroll
        for (int j = 0; j < 4; j++) {
            const int i = j * 256 + tid;
            const int r = i >> 3;
            const int sl = (i & 7) ^ (r & 7);
            const int ke = kt * 64 + sl * 8;
            async_copy16(lds + ABYTES + i * 16,
                         B + (size_t)(n0 + r) * KTOT + ke);
        }
    };

    const int l15 = lane & 15, lq = lane >> 4, l7 = lane & 7;
    int kx[2];
#pragma unroll
    for (int ks = 0; ks < 2; ks++) kx[ks] = ((ks * 4 + lq) ^ l7) << 4;

#pragma unroll 1
    for (int kt = 0; kt < TB; kt++) {
        stage(kt);
        __syncthreads();                  // drains vmcnt -> buffer ready
        const char* sA = lds;
        const char* sB = lds + ABYTES;
#pragma unroll
        for (int ks = 0; ks < 2; ks++) {
            short8 a[8], b[4];
#pragma unroll
            for (int mi = 0; mi < 8; mi++)
                a[mi] = *(const short8*)(sA +
                    (size_t)(wm * 128 + mi * 16 + l15) * 128 + kx[ks]);
#pragma unroll
            for (int ni = 0; ni < 4; ni++)
                b[ni] = *(const short8*)(sB +
                    (size_t)(wn * 64 + ni * 16 + l15) * 128 + kx[ks]);
#pragma unroll
            for (int ni = 0; ni < 4; ni++)
#pragma unroll
                for (int mi = 0; mi < 8; mi++)
                    acc[mi][ni] = __builtin_amdgcn_mfma_f32_16x16x32_bf16(
                        a[mi], b[ni], acc[mi][ni], 0, 0, 0);
        }
        __syncthreads();                  // all reads done before next stage
    }

    // epilogue: C/D col = lane&15, row = mi*16 + lq*4 + r
#pragma unroll
    for (int ni = 0; ni < 4; ni++) {
        const int gcol = n0 + wn * 64 + ni * 16 + l15;
        if constexpr (EPI == 0) {
            const float bcl = bc[gcol];
#pragma unroll
            for (int mi = 0; mi < 8; mi++)
#pragma unroll
                for (int r = 0; r < 4; r++) {
                    const int m = m0 + wm * 128 + mi * 16 + lq * 4 + r;
                    ub[(size_t)m * 512 + gcol] =
                        __float2bfloat16(acc[mi][ni][r] + bcl);
                }
        } else {
            if (gcol < 512) {
                const float bil = bi[gcol];
#pragma unroll
                for (int mi = 0; mi < 8; mi++)
#pragma unroll
                    for (int r = 0; r < 4; r++) {
                        const int m = m0 + wm * 128 + mi * 16 + lq * 4 + r;
                        const size_t idx = (size_t)m * 512 + gcol;
                        const float iv =
                            1.f / (1.f + __expf(-(acc[mi][ni][r] + bil)));
                        const float uv = __bfloat162float(ub[idx]);
                        ub[idx] = __float2bfloat16(iv * uv);
                    }
            } else {
                const int l2 = gcol - 512;
                const float bgl = bg[l2];
#pragma unroll
                for (int mi = 0; mi < 8; mi++)
#pragma unroll
                    for (int r = 0; r < 4; r++) {
                        const int m = m0 + wm * 128 + mi * 16 + lq * 4 + r;
                        const float fv =
                            1.f / (1.f + __expf(-(acc[mi][ni][r] + bgl)));
                        fb[(size_t)m * 512 + l2] = __float2bfloat16(fv);
                    }
            }
        }
    }
}

// ---------------------------------------------------------------------------
// Kernel 3: sequential scan; h = sin(z)*c; out[b,l,t].
// ---------------------------------------------------------------------------
__global__ __launch_bounds__(64) void k3_scan(
    const __hip_bfloat16* __restrict__ zb,
    const __hip_bfloat16* __restrict__ fb,
    const __hip_bfloat16* __restrict__ ub,
    const float* __restrict__ init_c, float* __restrict__ out)
{
    const int b = blockIdx.x >> 3;
    const int l = ((blockIdx.x & 7) << 6) + threadIdx.x;
    float c = init_c[l];

    const __hip_bfloat16* zp = zb + (size_t)b * NT * 512 + l;
    const __hip_bfloat16* fp = fb + (size_t)b * NT * NL + l;
    const __hip_bfloat16* ip = ub + (size_t)b * NT * NL + l;
    float* op = out + ((size_t)b * NL + l) * NT;

    for (int t0 = 0; t0 < NT; t0 += 16) {
        float fv[16], iv[16], zv[16];
#pragma unroll
        for (int j = 0; j < 16; j++) {
            fv[j] = __bfloat162float(fp[(size_t)(t0 + j) * NL]);
            iv[j] = __bfloat162float(ip[(size_t)(t0 + j) * NL]);
            zv[j] = __bfloat162float(zp[(size_t)(t0 + j) * 512]);
        }
        float h[16];
#pragma unroll
        for (int j = 0; j < 16; j++) {
            c = fv[j] * c + iv[j];
            h[j] = __sinf(zv[j]) * c;
        }
        float4* o4 = (float4*)(op + t0);
        o4[0] = make_float4(h[0],  h[1],  h[2],  h[3]);
        o4[1] = make_float4(h[4],  h[5],  h[6],  h[7]);
        o4[2] = make_float4(h[8],  h[9],  h[10], h[11]);
        o4[3] = make_float4(h[12], h[13], h[14], h[15]);
    }
}

// ---------------------------------------------------------------------------
extern "C" void kernel_launch(void* const* d_in, const int* in_sizes, int n_in,
                              void* d_out, int out_size, void* d_ws, size_t ws_size,
                              hipStream_t stream)
{
    const float* x      = (const float*)d_in[0];
    const float* conn   = (const float*)d_in[1];
    const float* Wf     = (const float*)d_in[2];
    const float* bfv    = (const float*)d_in[3];
    const float* gamma  = (const float*)d_in[4];
    const float* beta   = (const float*)d_in[5];
    const float* Wi     = (const float*)d_in[6];
    const float* Ri     = (const float*)d_in[7];
    const float* bi     = (const float*)d_in[8];
    const float* Wg     = (const float*)d_in[9];
    const float* Rg     = (const float*)d_in[10];
    const float* bg     = (const float*)d_in[11];
    const float* Wc     = (const float*)d_in[12];
    const float* bc     = (const float*)d_in[13];
    const float* init_h = (const float*)d_in[14];
    const float* init_c = (const float*)d_in[15];

    char* w = (char*)d_ws;
    __hip_bfloat16* zbuf = (__hip_bfloat16*)w;  w += (size_t)M_TOT * 512 * 2;
    __hip_bfloat16* cbuf = (__hip_bfloat16*)w;  w += (size_t)M_TOT * NCONN * 2;
    __hip_bfloat16* fbuf = (__hip_bfloat16*)w;  w += (size_t)M_TOT * NL * 2;
    __hip_bfloat16* ubuf = (__hip_bfloat16*)w;  w += (size_t)M_TOT * NL * 2;
    __hip_bfloat16* xbuf = (__hip_bfloat16*)w;  w += (size_t)M_TOT * IN_DIM * 2;
    __hip_bfloat16* WfT  = (__hip_bfloat16*)w;  w += (size_t)NL * IN_DIM * 2;
    __hip_bfloat16* Btig = (__hip_bfloat16*)w;  w += (size_t)1024 * 1024 * 2;
    __hip_bfloat16* Btc  = (__hip_bfloat16*)w;  w += (size_t)NL * NCONN * 2;
    __hip_bfloat16* ihb  = (__hip_bfloat16*)w;  w += 512 * 2;

    // prep: Btig rows 0..511 = [Wi;Ri]^T, rows 512..1023 = [Wg;Rg]^T
    wconv_transpose<<<32, 256, 0, stream>>>(Wf, WfT, 256, 512, 256, 0);
    wconv_transpose<<<64, 256, 0, stream>>>(Wi, Btig, 512, 512, 1024, 0);
    wconv_transpose<<<64, 256, 0, stream>>>(Ri, Btig, 512, 512, 1024, 512);
    wconv_transpose<<<64, 256, 0, stream>>>(Wg, Btig + (size_t)512 * 1024, 512, 512, 1024, 0);
    wconv_transpose<<<64, 256, 0, stream>>>(Rg, Btig + (size_t)512 * 1024, 512, 512, 1024, 512);
    wconv_transpose<<<32, 256, 0, stream>>>(Wc, Btc, 256, 512, 256, 0);
    conv_bf16_vec<<<(M_TOT * NCONN / 4 + 255) / 256, 256, 0, stream>>>(
        conn, cbuf, M_TOT * NCONN);
    xprep_transpose<<<NB * 32, 256, 0, stream>>>(x, xbuf);
    fill_ihb<<<1, 512, 0, stream>>>(init_h, ihb);

    // z = LN(cos(x^T Wf + bf)) -> zbuf [M][512]
    k1_mfma_fourier_ln<<<M_TOT / 64, 512, 0, stream>>>(
        xbuf, WfT, bfv, gamma, beta, zbuf);

    // u = conn @ Wc + bc -> ubuf   (grid 64 x 4 = 256)
    gemm256<NCONN, 0><<<M_TOT / 256 * 4, 256, 0, stream>>>(
        cbuf, Btc, nullptr, nullptr, nullptr, bc, nullptr, ubuf);

    // merged gates: N=1024 over Btig; stitched A = [z | z_prev]  (grid 512)
    gemm256<1024, 1><<<M_TOT / 256 * 8, 256, 0, stream>>>(
        zbuf, Btig, ihb, bi, bg, nullptr, fbuf, ubuf);

    k3_scan<<<NB * 8, 64, 0, stream>>>(zbuf, fbuf, ubuf, init_c, (float*)d_out);
}

// Round 10
// 137.172 us; speedup vs baseline: 1.0017x; 1.0017x over previous
//
#include <hip/hip_runtime.h>
#include <hip/hip_bf16.h>

#define NB 32
#define IN_DIM 256
#define NT 512
#define NL 512
#define NCONN 256
#define LN_EPS 1e-3f
#define M_TOT (NB * NT)   // 16384 rows

typedef __attribute__((ext_vector_type(8))) short short8;
typedef __attribute__((ext_vector_type(4))) float f32x4;

__device__ __forceinline__ void async_copy16(void* lds_dst, const void* g_src) {
    __builtin_amdgcn_global_load_lds(
        (const __attribute__((address_space(1))) unsigned int*)g_src,
        (__attribute__((address_space(3))) unsigned int*)lds_dst, 16, 0, 0);
}

// ---------------------------------------------------------------------------
// x prep: Axt[b*512+t][k] = bf16(x[b][k][t])
// ---------------------------------------------------------------------------
__global__ __launch_bounds__(256) void xprep_transpose(
    const float* __restrict__ x, __hip_bfloat16* __restrict__ Axt)
{
    __shared__ float t[64][65];
    const int tilesPerB = (IN_DIM / 64) * (NT / 64);
    const int b  = blockIdx.x / tilesPerB;
    const int tl = blockIdx.x % tilesPerB;
    const int k0 = (tl / (NT / 64)) * 64;
    const int t0 = (tl % (NT / 64)) * 64;
    const int tid = threadIdx.x;
    const float* src = x + (size_t)b * IN_DIM * NT;
    for (int idx = tid; idx < 4096; idx += 256) {
        const int kk = idx >> 6, tt = idx & 63;
        t[kk][tt] = src[(size_t)(k0 + kk) * NT + t0 + tt];
    }
    __syncthreads();
    for (int idx = tid; idx < 4096; idx += 256) {
        const int tt = idx >> 6, kk = idx & 63;
        Axt[((size_t)b * NT + t0 + tt) * IN_DIM + k0 + kk] =
            __float2bfloat16(t[kk][tt]);
    }
}

__global__ void fill_ihb(const float* __restrict__ init_h,
                         __hip_bfloat16* __restrict__ ihb)
{
    const int l = threadIdx.x;
    ihb[l] = __float2bfloat16(init_h[l]);
}

// ---------------------------------------------------------------------------
// Kernel 1 (MFMA 16x16x32): P = Axt @ WfT^T (64 rows x 512 cols per block),
// p = cos(P+bf), LN over cols, write zbuf [M][512] bf16.
// ---------------------------------------------------------------------------
__global__ __launch_bounds__(512, 2) void k1_mfma_fourier_ln(
    const __hip_bfloat16* __restrict__ Axt,   // [M_TOT][256]
    const __hip_bfloat16* __restrict__ WfT,   // [512][256]
    const float* __restrict__ bf, const float* __restrict__ gamma,
    const float* __restrict__ beta,
    __hip_bfloat16* __restrict__ zb)
{
    constexpr int ABYTES = 64 * 128;          // 8 KB
    constexpr int BBYTES = 512 * 128;         // 64 KB
    constexpr int NBUFB  = ABYTES + BBYTES;
    __shared__ __align__(16) char lds[2 * NBUFB];     // 144 KB
    __shared__ float pS[64][8], pQ[64][8];
    __shared__ float mS[64], rS[64];

    const int tid  = threadIdx.x;
    const int wave = tid >> 6, lane = tid & 63;
    const int m0 = blockIdx.x * 64;

    f32x4 acc[4][4];
#pragma unroll
    for (int mi = 0; mi < 4; mi++)
#pragma unroll
        for (int ni = 0; ni < 4; ni++) acc[mi][ni] = f32x4{0.f, 0.f, 0.f, 0.f};

    const int rowq = tid >> 3;
    const int sswz = ((tid & 7) ^ (rowq & 7)) << 4;
    const char* Ab = (const char*)Axt;
    const char* Bb = (const char*)WfT;

    auto stage = [&](int buf, int kt) {
        const size_t kb = (size_t)kt * 128;
        char* base = lds + buf * NBUFB;
        async_copy16(base + tid * 16,
                     Ab + (size_t)(m0 + rowq) * 512 + kb + sswz);
#pragma unroll
        for (int j = 0; j < 8; j++) {
            const int row = j * 64 + rowq;
            async_copy16(base + ABYTES + (j * 512 + tid) * 16,
                         Bb + (size_t)row * 512 + kb + sswz);
        }
    };

    const int l15 = lane & 15, lq = lane >> 4, l7 = lane & 7;
    int kxB[2];
#pragma unroll
    for (int ks = 0; ks < 2; ks++) kxB[ks] = ((ks * 4 + lq) ^ l7) << 4;

    stage(0, 0);
    int cur = 0;
#pragma unroll 1
    for (int kt = 0; kt < 4; kt++) {
        __syncthreads();
        if (kt + 1 < 4) stage(cur ^ 1, kt + 1);
        const char* sA = lds + cur * NBUFB;
        const char* sB = sA + ABYTES;
#pragma unroll
        for (int ks = 0; ks < 2; ks++) {
            const int kx = kxB[ks];
            short8 a[4], b[4];
#pragma unroll
            for (int mi = 0; mi < 4; mi++)
                a[mi] = *(const short8*)(sA + (size_t)(mi * 16 + l15) * 128 + kx);
#pragma unroll
            for (int ni = 0; ni < 4; ni++)
                b[ni] = *(const short8*)(sB +
                    (size_t)(wave * 64 + ni * 16 + l15) * 128 + kx);
#pragma unroll
            for (int ni = 0; ni < 4; ni++)
#pragma unroll
                for (int mi = 0; mi < 4; mi++)
                    acc[mi][ni] = __builtin_amdgcn_mfma_f32_16x16x32_bf16(
                        a[mi], b[ni], acc[mi][ni], 0, 0, 0);
        }
        cur ^= 1;
    }

    int cg[4]; float bfc[4];
#pragma unroll
    for (int ni = 0; ni < 4; ni++) {
        cg[ni] = wave * 64 + ni * 16 + l15;
        bfc[ni] = bf[cg[ni]];
    }

#pragma unroll
    for (int mi = 0; mi < 4; mi++) {
#pragma unroll
        for (int r = 0; r < 4; r++) {
            float s = 0.f, q = 0.f;
#pragma unroll
            for (int ni = 0; ni < 4; ni++) {
                const float p = __cosf(acc[mi][ni][r] + bfc[ni]);
                s += p; q += p * p;
            }
#pragma unroll
            for (int off = 8; off >= 1; off >>= 1) {
                s += __shfl_xor(s, off);
                q += __shfl_xor(q, off);
            }
            if (l15 == 0) {
                const int row = mi * 16 + lq * 4 + r;
                pS[row][wave] = s;
                pQ[row][wave] = q;
            }
        }
    }
    __syncthreads();
    if (tid < 64) {
        float a = 0.f, qq = 0.f;
#pragma unroll
        for (int w = 0; w < 8; w++) { a += pS[tid][w]; qq += pQ[tid][w]; }
        const float mu = a * (1.0f / NL);
        const float var = qq * (1.0f / NL) - mu * mu;
        mS[tid] = mu;
        rS[tid] = rsqrtf(var + LN_EPS);
    }
    __syncthreads();

    float gm[4], bt[4];
#pragma unroll
    for (int ni = 0; ni < 4; ni++) { gm[ni] = gamma[cg[ni]]; bt[ni] = beta[cg[ni]]; }

#pragma unroll
    for (int mi = 0; mi < 4; mi++) {
#pragma unroll
        for (int r = 0; r < 4; r++) {
            const int row = mi * 16 + lq * 4 + r;
            const int m = m0 + row;
            const float mu = mS[row], rs = rS[row];
#pragma unroll
            for (int ni = 0; ni < 4; ni++) {
                const float p = __cosf(acc[mi][ni][r] + bfc[ni]);
                const float z = gm[ni] * (p - mu) * rs + bt[ni];
                zb[(size_t)m * 512 + cg[ni]] = __float2bfloat16(z);
            }
        }
    }
}

// ---------------------------------------------------------------------------
// Weight transpose+convert / conn convert
// ---------------------------------------------------------------------------
__global__ __launch_bounds__(256) void wconv_transpose(
    const float* __restrict__ src, __hip_bfloat16* __restrict__ dst,
    int K, int N, int lddst, int k_off)
{
    __shared__ float t[64][65];
    const int ntn = N >> 6;
    const int k0 = (blockIdx.x / ntn) << 6;
    const int n0 = (blockIdx.x % ntn) << 6;
    const int tid = threadIdx.x;
    for (int idx = tid; idx < 4096; idx += 256) {
        const int kk = idx >> 6, nn = idx & 63;
        t[kk][nn] = src[(size_t)(k0 + kk) * N + n0 + nn];
    }
    __syncthreads();
    for (int idx = tid; idx < 4096; idx += 256) {
        const int nn = idx >> 6, kk = idx & 63;
        dst[(size_t)(n0 + nn) * lddst + k_off + k0 + kk] = __float2bfloat16(t[kk][nn]);
    }
}

__global__ __launch_bounds__(256) void conv_bf16_vec(
    const float* __restrict__ src, __hip_bfloat16* __restrict__ dst, int n)
{
    const int e = (blockIdx.x * 256 + threadIdx.x) * 4;
    if (e < n) {
        const float4 v = *(const float4*)(src + e);
        dst[e + 0] = __float2bfloat16(v.x);
        dst[e + 1] = __float2bfloat16(v.y);
        dst[e + 2] = __float2bfloat16(v.z);
        dst[e + 3] = __float2bfloat16(v.w);
    }
}

// ---------------------------------------------------------------------------
// u-GEMM (R8-proven gemm128 structure): 128x128 tile, BK=64, 4 waves,
// dbuf stage-ahead, ub[m][n] = bf16(conn@Wc + bc).
// ---------------------------------------------------------------------------
__global__ __launch_bounds__(256, 2) void gemm_u(
    const __hip_bfloat16* __restrict__ A,     // cbuf [M][256]
    const __hip_bfloat16* __restrict__ B,     // Btc  [512][256]
    const float* __restrict__ bc,
    __hip_bfloat16* __restrict__ ub)
{
    constexpr int KTOT = 256;
    constexpr int TB = KTOT / 64;
    __shared__ __align__(16) char lds[2][32768];

    const int tid  = threadIdx.x;
    const int wave = tid >> 6, lane = tid & 63;
    const int wm = wave >> 1, wn = wave & 1;
    const int d = blockIdx.x;
    const int L = (d & 7) * 64 + (d >> 3);
    const int m0 = (L >> 2) << 7;
    const int n0 = (L & 3) << 7;

    f32x4 acc[4][4];
#pragma unroll
    for (int mi = 0; mi < 4; mi++)
#pragma unroll
        for (int ni = 0; ni < 4; ni++) acc[mi][ni] = f32x4{0.f, 0.f, 0.f, 0.f};

    auto stage = [&](int buf, int kt) {
        char* base = &lds[buf][0];
#pragma unroll
        for (int j = 0; j < 4; j++) {
            const int i = j * 256 + tid;
            const int r = i >> 3;
            const int sl = (i & 7) ^ (r & 7);
            const int ke = kt * 64 + sl * 8;
            async_copy16(base + i * 16, A + (size_t)(m0 + r) * KTOT + ke);
            async_copy16(base + 16384 + i * 16, B + (size_t)(n0 + r) * KTOT + ke);
        }
    };

    const int l15 = lane & 15, lq = lane >> 4, l7 = lane & 7;
    int kx[2];
#pragma unroll
    for (int ks = 0; ks < 2; ks++) kx[ks] = ((ks * 4 + lq) ^ l7) << 4;

    stage(0, 0);
    int cur = 0;
#pragma unroll 1
    for (int kt = 0; kt < TB; kt++) {
        __syncthreads();
        if (kt + 1 < TB) stage(cur ^ 1, kt + 1);
        const char* sA = &lds[cur][0];
        const char* sB = &lds[cur][16384];
#pragma unroll
        for (int ks = 0; ks < 2; ks++) {
            short8 a[4], b[4];
#pragma unroll
            for (int mi = 0; mi < 4; mi++)
                a[mi] = *(const short8*)(sA +
                    (size_t)(wm * 64 + mi * 16 + l15) * 128 + kx[ks]);
#pragma unroll
            for (int ni = 0; ni < 4; ni++)
                b[ni] = *(const short8*)(sB +
                    (size_t)(wn * 64 + ni * 16 + l15) * 128 + kx[ks]);
#pragma unroll
            for (int ni = 0; ni < 4; ni++)
#pragma unroll
                for (int mi = 0; mi < 4; mi++)
                    acc[mi][ni] = __builtin_amdgcn_mfma_f32_16x16x32_bf16(
                        a[mi], b[ni], acc[mi][ni], 0, 0, 0);
        }
        cur ^= 1;
    }

#pragma unroll
    for (int ni = 0; ni < 4; ni++) {
        const int gcol = n0 + wn * 64 + ni * 16 + l15;
        const float bcl = bc[gcol];
#pragma unroll
        for (int mi = 0; mi < 4; mi++)
#pragma unroll
            for (int r = 0; r < 4; r++) {
                const int m = m0 + wm * 64 + mi * 16 + lq * 4 + r;
                ub[(size_t)m * 512 + gcol] =
                    __float2bfloat16(acc[mi][ni][r] + bcl);
            }
    }
}

// ---------------------------------------------------------------------------
// Gates: 8-phase counted-vmcnt MFMA GEMM (m201 port).
// 256x256 tile, 8 waves (2Mx4N, wave tile 128x64, acc[8][4]), BK=64 K-tiles,
// dbuf 128 KB, grid 256 = 1/CU. Per K-tile: issue H1(t+1) -> vmcnt(2) ->
// barrier -> 4 phases {ds_reads | stage half -> barrier -> setprio+16 MFMA
// -> barrier}. Never drains vmcnt in the main loop.
// A stitched: K<512 from zbuf[m], K>=512 from zbuf[m-1] / ihb at t=0.
// B = Btig [1024][1024]. Epilogue: n0<512: iu = sigmoid(acc+bi)*ub -> ub;
// else f = sigmoid(acc+bg) -> fb.
// ---------------------------------------------------------------------------
__global__ __launch_bounds__(512, 2) void gates8ph(
    const __hip_bfloat16* __restrict__ Az,
    const __hip_bfloat16* __restrict__ B,
    const __hip_bfloat16* __restrict__ ihb,
    const float* __restrict__ bi, const float* __restrict__ bg,
    __hip_bfloat16* __restrict__ fb, __hip_bfloat16* __restrict__ ub)
{
    constexpr int T = 16;                       // 1024 / 64
    __shared__ __align__(16) char lds[2][65536];

    const int tid  = threadIdx.x;
    const int wave = tid >> 6, lane = tid & 63;
    const int wm = wave >> 2, wn = wave & 3;    // 2 x 4 wave grid
    const int d = blockIdx.x;
    const int L = ((d & 7) << 5) | (d >> 3);    // 256 blocks, bijective
    const int m0 = (L >> 2) << 8;
    const int n0 = (L & 3) << 8;

    f32x4 acc[8][4];
#pragma unroll
    for (int mi = 0; mi < 8; mi++)
#pragma unroll
        for (int ni = 0; ni < 4; ni++) acc[mi][ni] = f32x4{0.f, 0.f, 0.f, 0.f};

    const int l15 = lane & 15, lq = lane >> 4, l7 = lane & 7;
    const int kx0 = (lq ^ l7) << 4;
    const int kx1 = ((4 + lq) ^ l7) << 4;

    // half: 0=A rows m0..+127, 1=A rows +128..255, 2=B rows n0..+127, 3=B +128..255
    auto stage_half = [&](int buf, int kt, int half) {
#pragma unroll
        for (int j = 0; j < 2; j++) {
            const int i = j * 512 + tid;
            const int r = i >> 3;                       // 0..127
            const int sl = (i & 7) ^ (r & 7);
            const int ke = kt * 64 + sl * 8;
            const __hip_bfloat16* src;
            if (half < 2) {
                const int m = m0 + half * 128 + r;
                if (ke < 512) {
                    src = Az + (size_t)m * 512 + ke;
                } else {
                    const int k2 = ke - 512;
                    src = ((m & (NT - 1)) == 0) ? (ihb + k2)
                                                : (Az + (size_t)(m - 1) * 512 + k2);
                }
            } else {
                const int nr = n0 + (half - 2) * 128 + r;
                src = B + (size_t)nr * 1024 + ke;
            }
            const int region = (half < 2) ? half * 16384
                                          : 32768 + (half - 2) * 16384;
            async_copy16(&lds[buf][region + i * 16], src);
        }
    };

    // prologue: tile 0 fully staged into buf 0 (8 loads per wave)
    stage_half(0, 0, 0); stage_half(0, 0, 1);
    stage_half(0, 0, 2); stage_half(0, 0, 3);

    int p = 0;
#pragma unroll 1
    for (int t = 0; t < T; t++) {
        const int q = p ^ 1;
        const bool st = (t + 1 < T);
        if (st) {
            stage_half(q, t + 1, 0);                    // H1 of next tile
            asm volatile("s_waitcnt vmcnt(2)" ::: "memory");
        } else {
            asm volatile("s_waitcnt vmcnt(0)" ::: "memory");
        }
        __builtin_amdgcn_sched_barrier(0);
        __builtin_amdgcn_s_barrier();                   // tile t ready (all waves)
        const char* bufp = lds[p];
        short8 b_[4];

#define GPHASE(MH, KXS, READB, DOSTAGE, STHALF)                               \
        {                                                                     \
            short8 a_[4];                                                     \
            _Pragma("unroll")                                                 \
            for (int mi = 0; mi < 4; mi++)                                    \
                a_[mi] = *(const short8*)(bufp +                              \
                    (size_t)(wm * 128 + MH * 64 + mi * 16 + l15) * 128 + KXS);\
            if (READB) {                                                      \
                _Pragma("unroll")                                             \
                for (int ni = 0; ni < 4; ni++)                                \
                    b_[ni] = *(const short8*)(bufp + 32768 +                  \
                        (size_t)(wn * 64 + ni * 16 + l15) * 128 + KXS);       \
            }                                                                 \
            if (DOSTAGE) stage_half(q, t + 1, STHALF);                        \
            __builtin_amdgcn_s_barrier();                                     \
            __builtin_amdgcn_s_setprio(1);                                    \
            _Pragma("unroll")                                                 \
            for (int ni = 0; ni < 4; ni++)                                    \
                _Pragma("unroll")                                             \
                for (int mi = 0; mi < 4; mi++)                                \
                    acc[MH * 4 + mi][ni] =                                    \
                        __builtin_amdgcn_mfma_f32_16x16x32_bf16(              \
                            a_[mi], b_[ni], acc[MH * 4 + mi][ni], 0, 0, 0);   \
            __builtin_amdgcn_s_setprio(0);                                    \
            __builtin_amdgcn_s_barrier();                                     \
        }

        GPHASE(0, kx0, true,  st, 1)
        GPHASE(1, kx0, false, st, 2)
        GPHASE(0, kx1, true,  st, 3)
        GPHASE(1, kx1, false, false, 0)
#undef GPHASE
        p = q;
    }

    // epilogue: C/D col = lane&15, row = mi*16 + lq*4 + r; block-uniform type
#pragma unroll
    for (int ni = 0; ni < 4; ni++) {
        const int gcol = n0 + wn * 64 + ni * 16 + l15;
        if (n0 < 512) {
            const float bil = bi[gcol];
#pragma unroll
            for (int mi = 0; mi < 8; mi++)
#pragma unroll
                for (int r = 0; r < 4; r++) {
                    const int m = m0 + wm * 128 + mi * 16 + lq * 4 + r;
                    const size_t idx = (size_t)m * 512 + gcol;
                    const float iv =
                        1.f / (1.f + __expf(-(acc[mi][ni][r] + bil)));
                    ub[idx] = __float2bfloat16(iv * __bfloat162float(ub[idx]));
                }
        } else {
            const int g2 = gcol - 512;
            const float bgl = bg[g2];
#pragma unroll
            for (int mi = 0; mi < 8; mi++)
#pragma unroll
                for (int r = 0; r < 4; r++) {
                    const int m = m0 + wm * 128 + mi * 16 + lq * 4 + r;
                    const float fv =
                        1.f / (1.f + __expf(-(acc[mi][ni][r] + bgl)));
                    fb[(size_t)m * 512 + g2] = __float2bfloat16(fv);
                }
        }
    }
}

// ---------------------------------------------------------------------------
// Kernel 3: sequential scan; h = sin(z)*c; out[b,l,t].
// ---------------------------------------------------------------------------
__global__ __launch_bounds__(64) void k3_scan(
    const __hip_bfloat16* __restrict__ zb,
    const __hip_bfloat16* __restrict__ fb,
    const __hip_bfloat16* __restrict__ ub,
    const float* __restrict__ init_c, float* __restrict__ out)
{
    const int b = blockIdx.x >> 3;
    const int l = ((blockIdx.x & 7) << 6) + threadIdx.x;
    float c = init_c[l];

    const __hip_bfloat16* zp = zb + (size_t)b * NT * 512 + l;
    const __hip_bfloat16* fp = fb + (size_t)b * NT * NL + l;
    const __hip_bfloat16* ip = ub + (size_t)b * NT * NL + l;
    float* op = out + ((size_t)b * NL + l) * NT;

    for (int t0 = 0; t0 < NT; t0 += 16) {
        float fv[16], iv[16], zv[16];
#pragma unroll
        for (int j = 0; j < 16; j++) {
            fv[j] = __bfloat162float(fp[(size_t)(t0 + j) * NL]);
            iv[j] = __bfloat162float(ip[(size_t)(t0 + j) * NL]);
            zv[j] = __bfloat162float(zp[(size_t)(t0 + j) * 512]);
        }
        float h[16];
#pragma unroll
        for (int j = 0; j < 16; j++) {
            c = fv[j] * c + iv[j];
            h[j] = __sinf(zv[j]) * c;
        }
        float4* o4 = (float4*)(op + t0);
        o4[0] = make_float4(h[0],  h[1],  h[2],  h[3]);
        o4[1] = make_float4(h[4],  h[5],  h[6],  h[7]);
        o4[2] = make_float4(h[8],  h[9],  h[10], h[11]);
        o4[3] = make_float4(h[12], h[13], h[14], h[15]);
    }
}

// ---------------------------------------------------------------------------
extern "C" void kernel_launch(void* const* d_in, const int* in_sizes, int n_in,
                              void* d_out, int out_size, void* d_ws, size_t ws_size,
                              hipStream_t stream)
{
    const float* x      = (const float*)d_in[0];
    const float* conn   = (const float*)d_in[1];
    const float* Wf     = (const float*)d_in[2];
    const float* bfv    = (const float*)d_in[3];
    const float* gamma  = (const float*)d_in[4];
    const float* beta   = (const float*)d_in[5];
    const float* Wi     = (const float*)d_in[6];
    const float* Ri     = (const float*)d_in[7];
    const float* bi     = (const float*)d_in[8];
    const float* Wg     = (const float*)d_in[9];
    const float* Rg     = (const float*)d_in[10];
    const float* bg     = (const float*)d_in[11];
    const float* Wc     = (const float*)d_in[12];
    const float* bc     = (const float*)d_in[13];
    const float* init_h = (const float*)d_in[14];
    const float* init_c = (const float*)d_in[15];

    char* w = (char*)d_ws;
    __hip_bfloat16* zbuf = (__hip_bfloat16*)w;  w += (size_t)M_TOT * 512 * 2;
    __hip_bfloat16* cbuf = (__hip_bfloat16*)w;  w += (size_t)M_TOT * NCONN * 2;
    __hip_bfloat16* fbuf = (__hip_bfloat16*)w;  w += (size_t)M_TOT * NL * 2;
    __hip_bfloat16* ubuf = (__hip_bfloat16*)w;  w += (size_t)M_TOT * NL * 2;
    __hip_bfloat16* xbuf = (__hip_bfloat16*)w;  w += (size_t)M_TOT * IN_DIM * 2;
    __hip_bfloat16* WfT  = (__hip_bfloat16*)w;  w += (size_t)NL * IN_DIM * 2;
    __hip_bfloat16* Btig = (__hip_bfloat16*)w;  w += (size_t)1024 * 1024 * 2;
    __hip_bfloat16* Btc  = (__hip_bfloat16*)w;  w += (size_t)NL * NCONN * 2;
    __hip_bfloat16* ihb  = (__hip_bfloat16*)w;  w += 512 * 2;

    // prep: Btig rows 0..511 = [Wi;Ri]^T, rows 512..1023 = [Wg;Rg]^T
    wconv_transpose<<<32, 256, 0, stream>>>(Wf, WfT, 256, 512, 256, 0);
    wconv_transpose<<<64, 256, 0, stream>>>(Wi, Btig, 512, 512, 1024, 0);
    wconv_transpose<<<64, 256, 0, stream>>>(Ri, Btig, 512, 512, 1024, 512);
    wconv_transpose<<<64, 256, 0, stream>>>(Wg, Btig + (size_t)512 * 1024, 512, 512, 1024, 0);
    wconv_transpose<<<64, 256, 0, stream>>>(Rg, Btig + (size_t)512 * 1024, 512, 512, 1024, 512);
    wconv_transpose<<<32, 256, 0, stream>>>(Wc, Btc, 256, 512, 256, 0);
    conv_bf16_vec<<<(M_TOT * NCONN / 4 + 255) / 256, 256, 0, stream>>>(
        conn, cbuf, M_TOT * NCONN);
    xprep_transpose<<<NB * 32, 256, 0, stream>>>(x, xbuf);
    fill_ihb<<<1, 512, 0, stream>>>(init_h, ihb);

    // z = LN(cos(x^T Wf + bf)) -> zbuf [M][512]
    k1_mfma_fourier_ln<<<M_TOT / 64, 512, 0, stream>>>(
        xbuf, WfT, bfv, gamma, beta, zbuf);

    // u = conn @ Wc + bc -> ubuf   (grid 512)
    gemm_u<<<M_TOT / 128 * 4, 256, 0, stream>>>(cbuf, Btc, bc, ubuf);

    // gates: 8-phase, grid 256 (= 1 block/CU)
    gates8ph<<<256, 512, 0, stream>>>(zbuf, Btig, ihb, bi, bg, fbuf, ubuf);

    k3_scan<<<NB * 8, 64, 0, stream>>>(zbuf, fbuf, ubuf, init_c, (float*)d_out);
}

// Round 11
// 132.991 us; speedup vs baseline: 1.0331x; 1.0314x over previous
//
#include <hip/hip_runtime.h>
#include <hip/hip_bf16.h>

#define NB 32
#define IN_DIM 256
#define NT 512
#define NL 512
#define NCONN 256
#define LN_EPS 1e-3f
#define M_TOT (NB * NT)   // 16384 rows

typedef __attribute__((ext_vector_type(8))) short short8;
typedef __attribute__((ext_vector_type(4))) float f32x4;

__device__ __forceinline__ void async_copy16(void* lds_dst, const void* g_src) {
    __builtin_amdgcn_global_load_lds(
        (const __attribute__((address_space(1))) unsigned int*)g_src,
        (__attribute__((address_space(3))) unsigned int*)lds_dst, 16, 0, 0);
}

// ---------------------------------------------------------------------------
// x prep: Axt[b*512+t][k] = bf16(x[b][k][t])
// ---------------------------------------------------------------------------
__global__ __launch_bounds__(256) void xprep_transpose(
    const float* __restrict__ x, __hip_bfloat16* __restrict__ Axt)
{
    __shared__ float t[64][65];
    const int tilesPerB = (IN_DIM / 64) * (NT / 64);
    const int b  = blockIdx.x / tilesPerB;
    const int tl = blockIdx.x % tilesPerB;
    const int k0 = (tl / (NT / 64)) * 64;
    const int t0 = (tl % (NT / 64)) * 64;
    const int tid = threadIdx.x;
    const float* src = x + (size_t)b * IN_DIM * NT;
    for (int idx = tid; idx < 4096; idx += 256) {
        const int kk = idx >> 6, tt = idx & 63;
        t[kk][tt] = src[(size_t)(k0 + kk) * NT + t0 + tt];
    }
    __syncthreads();
    for (int idx = tid; idx < 4096; idx += 256) {
        const int tt = idx >> 6, kk = idx & 63;
        Axt[((size_t)b * NT + t0 + tt) * IN_DIM + k0 + kk] =
            __float2bfloat16(t[kk][tt]);
    }
}

__global__ void fill_ihb(const float* __restrict__ init_h,
                         __hip_bfloat16* __restrict__ ihb)
{
    const int l = threadIdx.x;
    ihb[l] = __float2bfloat16(init_h[l]);
}

// ---------------------------------------------------------------------------
// Kernel 1 (MFMA 16x16x32): P = Axt @ WfT^T (64 rows x 512 cols per block),
// p = cos(P+bf), LN over cols, write zbuf [M][512] bf16.
// ---------------------------------------------------------------------------
__global__ __launch_bounds__(512, 2) void k1_mfma_fourier_ln(
    const __hip_bfloat16* __restrict__ Axt,   // [M_TOT][256]
    const __hip_bfloat16* __restrict__ WfT,   // [512][256]
    const float* __restrict__ bf, const float* __restrict__ gamma,
    const float* __restrict__ beta,
    __hip_bfloat16* __restrict__ zb)
{
    constexpr int ABYTES = 64 * 128;          // 8 KB
    constexpr int BBYTES = 512 * 128;         // 64 KB
    constexpr int NBUFB  = ABYTES + BBYTES;
    __shared__ __align__(16) char lds[2 * NBUFB];     // 144 KB
    __shared__ float pS[64][8], pQ[64][8];
    __shared__ float mS[64], rS[64];

    const int tid  = threadIdx.x;
    const int wave = tid >> 6, lane = tid & 63;
    const int m0 = blockIdx.x * 64;

    f32x4 acc[4][4];
#pragma unroll
    for (int mi = 0; mi < 4; mi++)
#pragma unroll
        for (int ni = 0; ni < 4; ni++) acc[mi][ni] = f32x4{0.f, 0.f, 0.f, 0.f};

    const int rowq = tid >> 3;
    const int sswz = ((tid & 7) ^ (rowq & 7)) << 4;
    const char* Ab = (const char*)Axt;
    const char* Bb = (const char*)WfT;

    auto stage = [&](int buf, int kt) {
        const size_t kb = (size_t)kt * 128;
        char* base = lds + buf * NBUFB;
        async_copy16(base + tid * 16,
                     Ab + (size_t)(m0 + rowq) * 512 + kb + sswz);
#pragma unroll
        for (int j = 0; j < 8; j++) {
            const int row = j * 64 + rowq;
            async_copy16(base + ABYTES + (j * 512 + tid) * 16,
                         Bb + (size_t)row * 512 + kb + sswz);
        }
    };

    const int l15 = lane & 15, lq = lane >> 4, l7 = lane & 7;
    int kxB[2];
#pragma unroll
    for (int ks = 0; ks < 2; ks++) kxB[ks] = ((ks * 4 + lq) ^ l7) << 4;

    stage(0, 0);
    int cur = 0;
#pragma unroll 1
    for (int kt = 0; kt < 4; kt++) {
        __syncthreads();
        if (kt + 1 < 4) stage(cur ^ 1, kt + 1);
        const char* sA = lds + cur * NBUFB;
        const char* sB = sA + ABYTES;
#pragma unroll
        for (int ks = 0; ks < 2; ks++) {
            const int kx = kxB[ks];
            short8 a[4], b[4];
#pragma unroll
            for (int mi = 0; mi < 4; mi++)
                a[mi] = *(const short8*)(sA + (size_t)(mi * 16 + l15) * 128 + kx);
#pragma unroll
            for (int ni = 0; ni < 4; ni++)
                b[ni] = *(const short8*)(sB +
                    (size_t)(wave * 64 + ni * 16 + l15) * 128 + kx);
#pragma unroll
            for (int ni = 0; ni < 4; ni++)
#pragma unroll
                for (int mi = 0; mi < 4; mi++)
                    acc[mi][ni] = __builtin_amdgcn_mfma_f32_16x16x32_bf16(
                        a[mi], b[ni], acc[mi][ni], 0, 0, 0);
        }
        cur ^= 1;
    }

    int cg[4]; float bfc[4];
#pragma unroll
    for (int ni = 0; ni < 4; ni++) {
        cg[ni] = wave * 64 + ni * 16 + l15;
        bfc[ni] = bf[cg[ni]];
    }

#pragma unroll
    for (int mi = 0; mi < 4; mi++) {
#pragma unroll
        for (int r = 0; r < 4; r++) {
            float s = 0.f, q = 0.f;
#pragma unroll
            for (int ni = 0; ni < 4; ni++) {
                const float p = __cosf(acc[mi][ni][r] + bfc[ni]);
                s += p; q += p * p;
            }
#pragma unroll
            for (int off = 8; off >= 1; off >>= 1) {
                s += __shfl_xor(s, off);
                q += __shfl_xor(q, off);
            }
            if (l15 == 0) {
                const int row = mi * 16 + lq * 4 + r;
                pS[row][wave] = s;
                pQ[row][wave] = q;
            }
        }
    }
    __syncthreads();
    if (tid < 64) {
        float a = 0.f, qq = 0.f;
#pragma unroll
        for (int w = 0; w < 8; w++) { a += pS[tid][w]; qq += pQ[tid][w]; }
        const float mu = a * (1.0f / NL);
        const float var = qq * (1.0f / NL) - mu * mu;
        mS[tid] = mu;
        rS[tid] = rsqrtf(var + LN_EPS);
    }
    __syncthreads();

    float gm[4], bt[4];
#pragma unroll
    for (int ni = 0; ni < 4; ni++) { gm[ni] = gamma[cg[ni]]; bt[ni] = beta[cg[ni]]; }

#pragma unroll
    for (int mi = 0; mi < 4; mi++) {
#pragma unroll
        for (int r = 0; r < 4; r++) {
            const int row = mi * 16 + lq * 4 + r;
            const int m = m0 + row;
            const float mu = mS[row], rs = rS[row];
#pragma unroll
            for (int ni = 0; ni < 4; ni++) {
                const float p = __cosf(acc[mi][ni][r] + bfc[ni]);
                const float z = gm[ni] * (p - mu) * rs + bt[ni];
                zb[(size_t)m * 512 + cg[ni]] = __float2bfloat16(z);
            }
        }
    }
}

// ---------------------------------------------------------------------------
// Weight transpose+convert / conn convert
// ---------------------------------------------------------------------------
__global__ __launch_bounds__(256) void wconv_transpose(
    const float* __restrict__ src, __hip_bfloat16* __restrict__ dst,
    int K, int N, int lddst, int k_off)
{
    __shared__ float t[64][65];
    const int ntn = N >> 6;
    const int k0 = (blockIdx.x / ntn) << 6;
    const int n0 = (blockIdx.x % ntn) << 6;
    const int tid = threadIdx.x;
    for (int idx = tid; idx < 4096; idx += 256) {
        const int kk = idx >> 6, nn = idx & 63;
        t[kk][nn] = src[(size_t)(k0 + kk) * N + n0 + nn];
    }
    __syncthreads();
    for (int idx = tid; idx < 4096; idx += 256) {
        const int nn = idx >> 6, kk = idx & 63;
        dst[(size_t)(n0 + nn) * lddst + k_off + k0 + kk] = __float2bfloat16(t[kk][nn]);
    }
}

__global__ __launch_bounds__(256) void conv_bf16_vec(
    const float* __restrict__ src, __hip_bfloat16* __restrict__ dst, int n)
{
    const int e = (blockIdx.x * 256 + threadIdx.x) * 4;
    if (e < n) {
        const float4 v = *(const float4*)(src + e);
        dst[e + 0] = __float2bfloat16(v.x);
        dst[e + 1] = __float2bfloat16(v.y);
        dst[e + 2] = __float2bfloat16(v.z);
        dst[e + 3] = __float2bfloat16(v.w);
    }
}

// ---------------------------------------------------------------------------
// m97-EXACT MFMA GEMM: 128x128 tile, BK=64, 4 waves (2x2, 64x64 wave-tile,
// 16x16x32 frags), SINGLE 32 KB LDS buffer, stage->barrier->compute->barrier.
// 32 KB LDS + ~88 VGPR -> up to 5 resident blocks/CU: cross-block overlap
// (m114 mechanism) hides staging latency. XCD-swizzled grid.
// EPI 0: ub[m][n] = bf16(acc + bc[n])                    (u-GEMM, KTOT=256)
// EPI 1: merged gates, B rows 0..511=[Wi;Ri]^T, 512..1023=[Wg;Rg]^T:
//        n<512: iu = sigmoid(acc+bi)*ub -> ub;  n>=512: f = sigmoid(acc+bg) -> fb
//        A stitched: K<512 from zbuf[m], K>=512 from zbuf[m-1] / ihb (t=0)
// ---------------------------------------------------------------------------
template<int KTOT, int EPI>
__global__ __launch_bounds__(256, 4) void gemm_sb(
    const __hip_bfloat16* __restrict__ A,
    const __hip_bfloat16* __restrict__ B,
    const __hip_bfloat16* __restrict__ ihb,
    const float* __restrict__ bi, const float* __restrict__ bg,
    const float* __restrict__ bc,
    __hip_bfloat16* __restrict__ fb, __hip_bfloat16* __restrict__ ub)
{
    constexpr int NTN = (EPI == 1) ? 8 : 4;   // N-tiles
    constexpr int TB  = KTOT / 64;            // K-steps
    __shared__ __align__(16) char lds[32768]; // A 16K | B 16K (single buffer)

    const int tid  = threadIdx.x;
    const int wave = tid >> 6, lane = tid & 63;
    const int wm = wave >> 1, wn = wave & 1;
    // XCD swizzle, m-major within XCD
    constexpr int CPX = 128 * NTN / 8;        // blocks per XCD
    const int d = blockIdx.x;
    const int L = (d & 7) * CPX + (d >> 3);
    const int m0 = (L / NTN) << 7;
    const int n0 = (L % NTN) << 7;

    f32x4 acc[4][4];
#pragma unroll
    for (int mi = 0; mi < 4; mi++)
#pragma unroll
        for (int ni = 0; ni < 4; ni++) acc[mi][ni] = f32x4{0.f, 0.f, 0.f, 0.f};

    auto stage = [&](int kt) {
#pragma unroll
        for (int j = 0; j < 4; j++) {
            const int i = j * 256 + tid;
            const int r = i >> 3;                       // tile row 0..127
            const int sl = (i & 7) ^ (r & 7);           // logical 16B slot
            const int ke = kt * 64 + sl * 8;            // K element offset
            const __hip_bfloat16* srcA;
            if constexpr (EPI == 1) {
                const int m = m0 + r;
                if (ke < 512) {
                    srcA = A + (size_t)m * 512 + ke;
                } else {
                    const int k2 = ke - 512;
                    srcA = ((m & (NT - 1)) == 0) ? (ihb + k2)
                                                 : (A + (size_t)(m - 1) * 512 + k2);
                }
            } else {
                srcA = A + (size_t)(m0 + r) * KTOT + ke;
            }
            async_copy16(lds + i * 16, srcA);
            async_copy16(lds + 16384 + i * 16,
                         B + (size_t)(n0 + r) * KTOT + ke);
        }
    };

    const int l15 = lane & 15, lq = lane >> 4, l7 = lane & 7;
    int kx[2];
#pragma unroll
    for (int ks = 0; ks < 2; ks++) kx[ks] = ((ks * 4 + lq) ^ l7) << 4;

#pragma unroll 1
    for (int kt = 0; kt < TB; kt++) {
        stage(kt);
        __syncthreads();                 // vmcnt(0) drain + barrier: tile ready
        const char* sA = lds;
        const char* sB = lds + 16384;
#pragma unroll
        for (int ks = 0; ks < 2; ks++) {
            short8 a[4], b[4];
#pragma unroll
            for (int mi = 0; mi < 4; mi++)
                a[mi] = *(const short8*)(sA +
                    (size_t)(wm * 64 + mi * 16 + l15) * 128 + kx[ks]);
#pragma unroll
            for (int ni = 0; ni < 4; ni++)
                b[ni] = *(const short8*)(sB +
                    (size_t)(wn * 64 + ni * 16 + l15) * 128 + kx[ks]);
#pragma unroll
            for (int ni = 0; ni < 4; ni++)
#pragma unroll
                for (int mi = 0; mi < 4; mi++)
                    acc[mi][ni] = __builtin_amdgcn_mfma_f32_16x16x32_bf16(
                        a[mi], b[ni], acc[mi][ni], 0, 0, 0);
        }
        __syncthreads();                 // reads done before next overwrite
    }

    // epilogue: C/D col = lane&15, row = mi*16 + lq*4 + r
#pragma unroll
    for (int ni = 0; ni < 4; ni++) {
        const int gcol = n0 + wn * 64 + ni * 16 + l15;
        if constexpr (EPI == 0) {
            const float bcl = bc[gcol];
#pragma unroll
            for (int mi = 0; mi < 4; mi++)
#pragma unroll
                for (int r = 0; r < 4; r++) {
                    const int m = m0 + wm * 64 + mi * 16 + lq * 4 + r;
                    ub[(size_t)m * 512 + gcol] =
                        __float2bfloat16(acc[mi][ni][r] + bcl);
                }
        } else {
            if (gcol < 512) {
                const float bil = bi[gcol];
#pragma unroll
                for (int mi = 0; mi < 4; mi++)
#pragma unroll
                    for (int r = 0; r < 4; r++) {
                        const int m = m0 + wm * 64 + mi * 16 + lq * 4 + r;
                        const size_t idx = (size_t)m * 512 + gcol;
                        const float iv =
                            1.f / (1.f + __expf(-(acc[mi][ni][r] + bil)));
                        const float uv = __bfloat162float(ub[idx]);
                        ub[idx] = __float2bfloat16(iv * uv);
                    }
            } else {
                const int l2 = gcol - 512;
                const float bgl = bg[l2];
#pragma unroll
                for (int mi = 0; mi < 4; mi++)
#pragma unroll
                    for (int r = 0; r < 4; r++) {
                        const int m = m0 + wm * 64 + mi * 16 + lq * 4 + r;
                        const float fv =
                            1.f / (1.f + __expf(-(acc[mi][ni][r] + bgl)));
                        fb[(size_t)m * 512 + l2] = __float2bfloat16(fv);
                    }
            }
        }
    }
}

// ---------------------------------------------------------------------------
// Kernel 3: sequential scan; h = sin(z)*c; out[b,l,t].
// ---------------------------------------------------------------------------
__global__ __launch_bounds__(64) void k3_scan(
    const __hip_bfloat16* __restrict__ zb,
    const __hip_bfloat16* __restrict__ fb,
    const __hip_bfloat16* __restrict__ ub,
    const float* __restrict__ init_c, float* __restrict__ out)
{
    const int b = blockIdx.x >> 3;
    const int l = ((blockIdx.x & 7) << 6) + threadIdx.x;
    float c = init_c[l];

    const __hip_bfloat16* zp = zb + (size_t)b * NT * 512 + l;
    const __hip_bfloat16* fp = fb + (size_t)b * NT * NL + l;
    const __hip_bfloat16* ip = ub + (size_t)b * NT * NL + l;
    float* op = out + ((size_t)b * NL + l) * NT;

    for (int t0 = 0; t0 < NT; t0 += 16) {
        float fv[16], iv[16], zv[16];
#pragma unroll
        for (int j = 0; j < 16; j++) {
            fv[j] = __bfloat162float(fp[(size_t)(t0 + j) * NL]);
            iv[j] = __bfloat162float(ip[(size_t)(t0 + j) * NL]);
            zv[j] = __bfloat162float(zp[(size_t)(t0 + j) * 512]);
        }
        float h[16];
#pragma unroll
        for (int j = 0; j < 16; j++) {
            c = fv[j] * c + iv[j];
            h[j] = __sinf(zv[j]) * c;
        }
        float4* o4 = (float4*)(op + t0);
        o4[0] = make_float4(h[0],  h[1],  h[2],  h[3]);
        o4[1] = make_float4(h[4],  h[5],  h[6],  h[7]);
        o4[2] = make_float4(h[8],  h[9],  h[10], h[11]);
        o4[3] = make_float4(h[12], h[13], h[14], h[15]);
    }
}

// ---------------------------------------------------------------------------
extern "C" void kernel_launch(void* const* d_in, const int* in_sizes, int n_in,
                              void* d_out, int out_size, void* d_ws, size_t ws_size,
                              hipStream_t stream)
{
    const float* x      = (const float*)d_in[0];
    const float* conn   = (const float*)d_in[1];
    const float* Wf     = (const float*)d_in[2];
    const float* bfv    = (const float*)d_in[3];
    const float* gamma  = (const float*)d_in[4];
    const float* beta   = (const float*)d_in[5];
    const float* Wi     = (const float*)d_in[6];
    const float* Ri     = (const float*)d_in[7];
    const float* bi     = (const float*)d_in[8];
    const float* Wg     = (const float*)d_in[9];
    const float* Rg     = (const float*)d_in[10];
    const float* bg     = (const float*)d_in[11];
    const float* Wc     = (const float*)d_in[12];
    const float* bc     = (const float*)d_in[13];
    const float* init_h = (const float*)d_in[14];
    const float* init_c = (const float*)d_in[15];

    char* w = (char*)d_ws;
    __hip_bfloat16* zbuf = (__hip_bfloat16*)w;  w += (size_t)M_TOT * 512 * 2;
    __hip_bfloat16* cbuf = (__hip_bfloat16*)w;  w += (size_t)M_TOT * NCONN * 2;
    __hip_bfloat16* fbuf = (__hip_bfloat16*)w;  w += (size_t)M_TOT * NL * 2;
    __hip_bfloat16* ubuf = (__hip_bfloat16*)w;  w += (size_t)M_TOT * NL * 2;
    __hip_bfloat16* xbuf = (__hip_bfloat16*)w;  w += (size_t)M_TOT * IN_DIM * 2;
    __hip_bfloat16* WfT  = (__hip_bfloat16*)w;  w += (size_t)NL * IN_DIM * 2;
    __hip_bfloat16* Btig = (__hip_bfloat16*)w;  w += (size_t)1024 * 1024 * 2;
    __hip_bfloat16* Btc  = (__hip_bfloat16*)w;  w += (size_t)NL * NCONN * 2;
    __hip_bfloat16* ihb  = (__hip_bfloat16*)w;  w += 512 * 2;

    // prep: Btig rows 0..511 = [Wi;Ri]^T, rows 512..1023 = [Wg;Rg]^T
    wconv_transpose<<<32, 256, 0, stream>>>(Wf, WfT, 256, 512, 256, 0);
    wconv_transpose<<<64, 256, 0, stream>>>(Wi, Btig, 512, 512, 1024, 0);
    wconv_transpose<<<64, 256, 0, stream>>>(Ri, Btig, 512, 512, 1024, 512);
    wconv_transpose<<<64, 256, 0, stream>>>(Wg, Btig + (size_t)512 * 1024, 512, 512, 1024, 0);
    wconv_transpose<<<64, 256, 0, stream>>>(Rg, Btig + (size_t)512 * 1024, 512, 512, 1024, 512);
    wconv_transpose<<<32, 256, 0, stream>>>(Wc, Btc, 256, 512, 256, 0);
    conv_bf16_vec<<<(M_TOT * NCONN / 4 + 255) / 256, 256, 0, stream>>>(
        conn, cbuf, M_TOT * NCONN);
    xprep_transpose<<<NB * 32, 256, 0, stream>>>(x, xbuf);
    fill_ihb<<<1, 512, 0, stream>>>(init_h, ihb);

    // z = LN(cos(x^T Wf + bf)) -> zbuf [M][512]
    k1_mfma_fourier_ln<<<M_TOT / 64, 512, 0, stream>>>(
        xbuf, WfT, bfv, gamma, beta, zbuf);

    // u = conn @ Wc + bc -> ubuf   (grid 512)
    gemm_sb<NCONN, 0><<<M_TOT / 128 * 4, 256, 0, stream>>>(
        cbuf, Btc, nullptr, nullptr, nullptr, bc, nullptr, ubuf);

    // merged gates: N=1024 over Btig; stitched A = [z | z_prev]  (grid 1024)
    gemm_sb<1024, 1><<<M_TOT / 128 * 8, 256, 0, stream>>>(
        zbuf, Btig, ihb, bi, bg, nullptr, fbuf, ubuf);

    k3_scan<<<NB * 8, 64, 0, stream>>>(zbuf, fbuf, ubuf, init_c, (float*)d_out);
}

// Round 12
// 129.746 us; speedup vs baseline: 1.0590x; 1.0250x over previous
//
#include <hip/hip_runtime.h>
#include <hip/hip_bf16.h>

#define NB 32
#define IN_DIM 256
#define NT 512
#define NL 512
#define NCONN 256
#define LN_EPS 1e-3f
#define M_TOT (NB * NT)   // 16384 rows

typedef __attribute__((ext_vector_type(8))) short short8;
typedef __attribute__((ext_vector_type(4))) float f32x4;

__device__ __forceinline__ void async_copy16(void* lds_dst, const void* g_src) {
    __builtin_amdgcn_global_load_lds(
        (const __attribute__((address_space(1))) unsigned int*)g_src,
        (__attribute__((address_space(3))) unsigned int*)lds_dst, 16, 0, 0);
}

__device__ __forceinline__ ushort f2bf(float f) {   // RNE f32->bf16 bits
    unsigned int x = __float_as_uint(f);
    return (ushort)((x + 0x7FFFu + ((x >> 16) & 1u)) >> 16);
}

__global__ void fill_ihb(const float* __restrict__ init_h,
                         __hip_bfloat16* __restrict__ ihb)
{
    const int l = threadIdx.x;
    ihb[l] = __float2bfloat16(init_h[l]);
}

// ---------------------------------------------------------------------------
// Kernel 1 (MFMA 16x16x32): P = x^T @ Wf (64 t-rows x 512 cols per block),
// A staged IN-KERNEL from f32 x[b][k][t] (transpose+convert scatter),
// p = cos(P+bf), LN over cols, write zbuf [M][512] bf16.
// ---------------------------------------------------------------------------
__global__ __launch_bounds__(512, 2) void k1_mfma_fourier_ln(
    const float* __restrict__ x,              // [NB][256][512] f32
    const __hip_bfloat16* __restrict__ WfT,   // [512][256]
    const float* __restrict__ bf, const float* __restrict__ gamma,
    const float* __restrict__ beta,
    __hip_bfloat16* __restrict__ zb)
{
    constexpr int ABYTES = 64 * 128;          // 8 KB
    constexpr int BBYTES = 512 * 128;         // 64 KB
    constexpr int NBUFB  = ABYTES + BBYTES;
    __shared__ __align__(16) char lds[2 * NBUFB];     // 144 KB
    __shared__ float pS[64][8], pQ[64][8];
    __shared__ float mS[64], rS[64];

    const int tid  = threadIdx.x;
    const int wave = tid >> 6, lane = tid & 63;
    const int m0 = blockIdx.x * 64;
    const int b  = m0 >> 9;
    const int t0 = m0 & 511;
    const float* xb = x + (size_t)b * IN_DIM * NT;

    f32x4 acc[4][4];
#pragma unroll
    for (int mi = 0; mi < 4; mi++)
#pragma unroll
        for (int ni = 0; ni < 4; ni++) acc[mi][ni] = f32x4{0.f, 0.f, 0.f, 0.f};

    const int rowq = tid >> 3;
    const int sswz = ((tid & 7) ^ (rowq & 7)) << 4;
    const char* Bb = (const char*)WfT;

    auto stage = [&](int buf, int kt) {
        char* base = lds + buf * NBUFB;
        // A: x f32 -> bf16 transposed [t][k], swizzled 16B slots
#pragma unroll
        for (int j = 0; j < 2; j++) {
            const int ci = j * 512 + tid;     // 0..1023
            const int k  = ci >> 4;           // 0..63 (K within step)
            const int tc = ci & 15;           // t-chunk (4 t each)
            const float4 v = *(const float4*)(
                xb + ((size_t)(kt * 64 + k)) * NT + t0 + tc * 4);
            const ushort h[4] = {f2bf(v.x), f2bf(v.y), f2bf(v.z), f2bf(v.w)};
            const int sl = k >> 3, kb2 = (k & 7) << 1;
#pragma unroll
            for (int e = 0; e < 4; e++) {
                const int t = tc * 4 + e;
                *(ushort*)(base + t * 128 + (((sl) ^ (t & 7)) << 4) + kb2) = h[e];
            }
        }
        // B: WfT async, pre-swizzled source
        const size_t kb = (size_t)kt * 128;
#pragma unroll
        for (int j = 0; j < 8; j++) {
            const int row = j * 64 + rowq;
            async_copy16(base + ABYTES + (j * 512 + tid) * 16,
                         Bb + (size_t)row * 512 + kb + sswz);
        }
    };

    const int l15 = lane & 15, lq = lane >> 4, l7 = lane & 7;
    int kxB[2];
#pragma unroll
    for (int ks = 0; ks < 2; ks++) kxB[ks] = ((ks * 4 + lq) ^ l7) << 4;

    stage(0, 0);
    int cur = 0;
#pragma unroll 1
    for (int kt = 0; kt < 4; kt++) {
        __syncthreads();
        if (kt + 1 < 4) stage(cur ^ 1, kt + 1);
        const char* sA = lds + cur * NBUFB;
        const char* sB = sA + ABYTES;
#pragma unroll
        for (int ks = 0; ks < 2; ks++) {
            const int kx = kxB[ks];
            short8 a[4], b[4];
#pragma unroll
            for (int mi = 0; mi < 4; mi++)
                a[mi] = *(const short8*)(sA + (size_t)(mi * 16 + l15) * 128 + kx);
#pragma unroll
            for (int ni = 0; ni < 4; ni++)
                b[ni] = *(const short8*)(sB +
                    (size_t)(wave * 64 + ni * 16 + l15) * 128 + kx);
#pragma unroll
            for (int ni = 0; ni < 4; ni++)
#pragma unroll
                for (int mi = 0; mi < 4; mi++)
                    acc[mi][ni] = __builtin_amdgcn_mfma_f32_16x16x32_bf16(
                        a[mi], b[ni], acc[mi][ni], 0, 0, 0);
        }
        cur ^= 1;
    }

    int cg[4]; float bfc[4];
#pragma unroll
    for (int ni = 0; ni < 4; ni++) {
        cg[ni] = wave * 64 + ni * 16 + l15;
        bfc[ni] = bf[cg[ni]];
    }

#pragma unroll
    for (int mi = 0; mi < 4; mi++) {
#pragma unroll
        for (int r = 0; r < 4; r++) {
            float s = 0.f, q = 0.f;
#pragma unroll
            for (int ni = 0; ni < 4; ni++) {
                const float p = __cosf(acc[mi][ni][r] + bfc[ni]);
                s += p; q += p * p;
            }
#pragma unroll
            for (int off = 8; off >= 1; off >>= 1) {
                s += __shfl_xor(s, off);
                q += __shfl_xor(q, off);
            }
            if (l15 == 0) {
                const int row = mi * 16 + lq * 4 + r;
                pS[row][wave] = s;
                pQ[row][wave] = q;
            }
        }
    }
    __syncthreads();
    if (tid < 64) {
        float a = 0.f, qq = 0.f;
#pragma unroll
        for (int w = 0; w < 8; w++) { a += pS[tid][w]; qq += pQ[tid][w]; }
        const float mu = a * (1.0f / NL);
        const float var = qq * (1.0f / NL) - mu * mu;
        mS[tid] = mu;
        rS[tid] = rsqrtf(var + LN_EPS);
    }
    __syncthreads();

    float gm[4], bt[4];
#pragma unroll
    for (int ni = 0; ni < 4; ni++) { gm[ni] = gamma[cg[ni]]; bt[ni] = beta[cg[ni]]; }

#pragma unroll
    for (int mi = 0; mi < 4; mi++) {
#pragma unroll
        for (int r = 0; r < 4; r++) {
            const int row = mi * 16 + lq * 4 + r;
            const int m = m0 + row;
            const float mu = mS[row], rs = rS[row];
#pragma unroll
            for (int ni = 0; ni < 4; ni++) {
                const float p = __cosf(acc[mi][ni][r] + bfc[ni]);
                const float z = gm[ni] * (p - mu) * rs + bt[ni];
                zb[(size_t)m * 512 + cg[ni]] = __float2bfloat16(z);
            }
        }
    }
}

// ---------------------------------------------------------------------------
// Weight transpose+convert
// ---------------------------------------------------------------------------
__global__ __launch_bounds__(256) void wconv_transpose(
    const float* __restrict__ src, __hip_bfloat16* __restrict__ dst,
    int K, int N, int lddst, int k_off)
{
    __shared__ float t[64][65];
    const int ntn = N >> 6;
    const int k0 = (blockIdx.x / ntn) << 6;
    const int n0 = (blockIdx.x % ntn) << 6;
    const int tid = threadIdx.x;
    for (int idx = tid; idx < 4096; idx += 256) {
        const int kk = idx >> 6, nn = idx & 63;
        t[kk][nn] = src[(size_t)(k0 + kk) * N + n0 + nn];
    }
    __syncthreads();
    for (int idx = tid; idx < 4096; idx += 256) {
        const int nn = idx >> 6, kk = idx & 63;
        dst[(size_t)(n0 + nn) * lddst + k_off + k0 + kk] = __float2bfloat16(t[kk][nn]);
    }
}

// ---------------------------------------------------------------------------
// Shared pieces for the gates kernels (128x128 tile, 4 waves, single 32 KB buf)
// Stitched-A staging: K<512 from zbuf[m], K>=512 from zbuf[m-1] / ihb (t=0).
// ---------------------------------------------------------------------------
#define GATES_PRELUDE                                                         \
    const int tid  = threadIdx.x;                                             \
    const int wave = tid >> 6, lane = tid & 63;                               \
    const int wm = wave >> 1, wn = wave & 1;                                  \
    const int d = blockIdx.x;                                                 \
    const int L = (d & 7) * 64 + (d >> 3);                                    \
    const int m0 = (L >> 2) << 7;                                             \
    const int n0 = (L & 3) << 7;                                              \
    const int l15 = lane & 15, lq = lane >> 4, l7 = lane & 7;                 \
    int kx[2];                                                                \
    kx[0] = (lq ^ l7) << 4;                                                   \
    kx[1] = ((4 + lq) ^ l7) << 4;

#define STAGE_AZ(kt)                                                          \
    {                                                                         \
        _Pragma("unroll")                                                     \
        for (int j = 0; j < 4; j++) {                                         \
            const int i = j * 256 + tid;                                      \
            const int r = i >> 3;                                             \
            const int sl = (i & 7) ^ (r & 7);                                 \
            const int ke = (kt) * 64 + sl * 8;                                \
            const __hip_bfloat16* srcA;                                       \
            const int m = m0 + r;                                             \
            if (ke < 512) {                                                   \
                srcA = Az + (size_t)m * 512 + ke;                             \
            } else {                                                          \
                const int k2 = ke - 512;                                      \
                srcA = ((m & (NT - 1)) == 0) ? (ihb + k2)                     \
                                             : (Az + (size_t)(m - 1) * 512 + k2); \
            }                                                                 \
            async_copy16(lds + i * 16, srcA);                                 \
            async_copy16(lds + 16384 + i * 16,                                \
                         Bg + (size_t)(n0 + r) * 1024 + ke);                  \
        }                                                                     \
    }

#define COMPUTE_TILE(ACC)                                                     \
    {                                                                         \
        const char* sA = lds;                                                 \
        const char* sB = lds + 16384;                                         \
        _Pragma("unroll")                                                     \
        for (int ks = 0; ks < 2; ks++) {                                      \
            short8 a[4], b[4];                                                \
            _Pragma("unroll")                                                 \
            for (int mi = 0; mi < 4; mi++)                                    \
                a[mi] = *(const short8*)(sA +                                 \
                    (size_t)(wm * 64 + mi * 16 + l15) * 128 + kx[ks]);        \
            _Pragma("unroll")                                                 \
            for (int ni = 0; ni < 4; ni++)                                    \
                b[ni] = *(const short8*)(sB +                                 \
                    (size_t)(wn * 64 + ni * 16 + l15) * 128 + kx[ks]);        \
            _Pragma("unroll")                                                 \
            for (int ni = 0; ni < 4; ni++)                                    \
                _Pragma("unroll")                                             \
                for (int mi = 0; mi < 4; mi++)                                \
                    ACC[mi][ni] = __builtin_amdgcn_mfma_f32_16x16x32_bf16(    \
                        a[mi], b[ni], ACC[mi][ni], 0, 0, 0);                  \
        }                                                                     \
    }

// ---------------------------------------------------------------------------
// gates_f: f = sigmoid([z|z_prev] @ [Wg;Rg]^T + bg) -> fbuf.  (Bg pre-offset)
// ---------------------------------------------------------------------------
__global__ __launch_bounds__(256, 4) void gates_f(
    const __hip_bfloat16* __restrict__ Az,
    const __hip_bfloat16* __restrict__ Bg,    // Btig + 512*1024
    const __hip_bfloat16* __restrict__ ihb,
    const float* __restrict__ bg,
    __hip_bfloat16* __restrict__ fb)
{
    __shared__ __align__(16) char lds[32768];
    GATES_PRELUDE

    f32x4 acc[4][4];
#pragma unroll
    for (int mi = 0; mi < 4; mi++)
#pragma unroll
        for (int ni = 0; ni < 4; ni++) acc[mi][ni] = f32x4{0.f, 0.f, 0.f, 0.f};

#pragma unroll 1
    for (int kt = 0; kt < 16; kt++) {
        STAGE_AZ(kt)
        __syncthreads();
        COMPUTE_TILE(acc)
        __syncthreads();
    }

#pragma unroll
    for (int ni = 0; ni < 4; ni++) {
        const int gcol = n0 + wn * 64 + ni * 16 + l15;
        const float bgl = bg[gcol];
#pragma unroll
        for (int mi = 0; mi < 4; mi++)
#pragma unroll
            for (int r = 0; r < 4; r++) {
                const int m = m0 + wm * 64 + mi * 16 + lq * 4 + r;
                const float fv = 1.f / (1.f + __expf(-(acc[mi][ni][r] + bgl)));
                fb[(size_t)m * 512 + gcol] = __float2bfloat16(fv);
            }
    }
}

// ---------------------------------------------------------------------------
// gates_iu: u-phase (conn f32 reg-staged @ Wc^T, K=256) then main GEMM
// ([z|z_prev] @ [Wi;Ri]^T, K=1024); iu = sigmoid(acc+bi)*(acc_u+bc) -> ubuf.
// ---------------------------------------------------------------------------
__global__ __launch_bounds__(256, 2) void gates_iu(
    const __hip_bfloat16* __restrict__ Az,
    const __hip_bfloat16* __restrict__ Bg,    // Btig (rows [Wi;Ri]^T)
    const float* __restrict__ conn,           // [M][256] f32
    const __hip_bfloat16* __restrict__ Btc,   // [512][256] Wc^T
    const __hip_bfloat16* __restrict__ ihb,
    const float* __restrict__ bi, const float* __restrict__ bc,
    __hip_bfloat16* __restrict__ ub)
{
    __shared__ __align__(16) char lds[32768];
    GATES_PRELUDE

    f32x4 accu[4][4];
#pragma unroll
    for (int mi = 0; mi < 4; mi++)
#pragma unroll
        for (int ni = 0; ni < 4; ni++) accu[mi][ni] = f32x4{0.f, 0.f, 0.f, 0.f};

    // ---- u phase: 4 K-steps over conn (f32 reg-staged) x Btc ----
#pragma unroll 1
    for (int kt = 0; kt < 4; kt++) {
        // A: conn f32 -> bf16, swizzled 16B slots (two 8B halves per slot)
#pragma unroll
        for (int j = 0; j < 8; j++) {
            const int ci = j * 256 + tid;     // 0..2047
            const int r  = ci >> 4;           // 0..127
            const int c4 = ci & 15;           // which float4 in row
            const float4 v = *(const float4*)(
                conn + (size_t)(m0 + r) * NCONN + kt * 64 + c4 * 4);
            ushort4 h;
            h.x = f2bf(v.x); h.y = f2bf(v.y); h.z = f2bf(v.z); h.w = f2bf(v.w);
            const int sl = c4 >> 1, half = c4 & 1;
            *(ushort4*)(lds + r * 128 + ((sl ^ (r & 7)) << 4) + half * 8) = h;
        }
        // B: Btc async
#pragma unroll
        for (int j = 0; j < 4; j++) {
            const int i = j * 256 + tid;
            const int r = i >> 3;
            const int sl = (i & 7) ^ (r & 7);
            const int ke = kt * 64 + sl * 8;
            async_copy16(lds + 16384 + i * 16,
                         Btc + (size_t)(n0 + r) * NCONN + ke);
        }
        __syncthreads();
        COMPUTE_TILE(accu)
        __syncthreads();
    }

    // ---- main phase: 16 K-steps over [z|z_prev] x [Wi;Ri]^T ----
    f32x4 acc[4][4];
#pragma unroll
    for (int mi = 0; mi < 4; mi++)
#pragma unroll
        for (int ni = 0; ni < 4; ni++) acc[mi][ni] = f32x4{0.f, 0.f, 0.f, 0.f};

#pragma unroll 1
    for (int kt = 0; kt < 16; kt++) {
        STAGE_AZ(kt)
        __syncthreads();
        COMPUTE_TILE(acc)
        __syncthreads();
    }

#pragma unroll
    for (int ni = 0; ni < 4; ni++) {
        const int gcol = n0 + wn * 64 + ni * 16 + l15;
        const float bil = bi[gcol], bcl = bc[gcol];
#pragma unroll
        for (int mi = 0; mi < 4; mi++)
#pragma unroll
            for (int r = 0; r < 4; r++) {
                const int m = m0 + wm * 64 + mi * 16 + lq * 4 + r;
                const float iv = 1.f / (1.f + __expf(-(acc[mi][ni][r] + bil)));
                const float uv = accu[mi][ni][r] + bcl;
                ub[(size_t)m * 512 + gcol] = __float2bfloat16(iv * uv);
            }
    }
}

// ---------------------------------------------------------------------------
// Kernel 3: sequential scan; h = sin(z)*c; out[b,l,t].
// ---------------------------------------------------------------------------
__global__ __launch_bounds__(64) void k3_scan(
    const __hip_bfloat16* __restrict__ zb,
    const __hip_bfloat16* __restrict__ fb,
    const __hip_bfloat16* __restrict__ ub,
    const float* __restrict__ init_c, float* __restrict__ out)
{
    const int b = blockIdx.x >> 3;
    const int l = ((blockIdx.x & 7) << 6) + threadIdx.x;
    float c = init_c[l];

    const __hip_bfloat16* zp = zb + (size_t)b * NT * 512 + l;
    const __hip_bfloat16* fp = fb + (size_t)b * NT * NL + l;
    const __hip_bfloat16* ip = ub + (size_t)b * NT * NL + l;
    float* op = out + ((size_t)b * NL + l) * NT;

    for (int t0 = 0; t0 < NT; t0 += 16) {
        float fv[16], iv[16], zv[16];
#pragma unroll
        for (int j = 0; j < 16; j++) {
            fv[j] = __bfloat162float(fp[(size_t)(t0 + j) * NL]);
            iv[j] = __bfloat162float(ip[(size_t)(t0 + j) * NL]);
            zv[j] = __bfloat162float(zp[(size_t)(t0 + j) * 512]);
        }
        float h[16];
#pragma unroll
        for (int j = 0; j < 16; j++) {
            c = fv[j] * c + iv[j];
            h[j] = __sinf(zv[j]) * c;
        }
        float4* o4 = (float4*)(op + t0);
        o4[0] = make_float4(h[0],  h[1],  h[2],  h[3]);
        o4[1] = make_float4(h[4],  h[5],  h[6],  h[7]);
        o4[2] = make_float4(h[8],  h[9],  h[10], h[11]);
        o4[3] = make_float4(h[12], h[13], h[14], h[15]);
    }
}

// ---------------------------------------------------------------------------
extern "C" void kernel_launch(void* const* d_in, const int* in_sizes, int n_in,
                              void* d_out, int out_size, void* d_ws, size_t ws_size,
                              hipStream_t stream)
{
    const float* x      = (const float*)d_in[0];
    const float* conn   = (const float*)d_in[1];
    const float* Wf     = (const float*)d_in[2];
    const float* bfv    = (const float*)d_in[3];
    const float* gamma  = (const float*)d_in[4];
    const float* beta   = (const float*)d_in[5];
    const float* Wi     = (const float*)d_in[6];
    const float* Ri     = (const float*)d_in[7];
    const float* bi     = (const float*)d_in[8];
    const float* Wg     = (const float*)d_in[9];
    const float* Rg     = (const float*)d_in[10];
    const float* bg     = (const float*)d_in[11];
    const float* Wc     = (const float*)d_in[12];
    const float* bc     = (const float*)d_in[13];
    const float* init_h = (const float*)d_in[14];
    const float* init_c = (const float*)d_in[15];

    char* w = (char*)d_ws;
    __hip_bfloat16* zbuf = (__hip_bfloat16*)w;  w += (size_t)M_TOT * 512 * 2;
    __hip_bfloat16* fbuf = (__hip_bfloat16*)w;  w += (size_t)M_TOT * NL * 2;
    __hip_bfloat16* ubuf = (__hip_bfloat16*)w;  w += (size_t)M_TOT * NL * 2;
    __hip_bfloat16* WfT  = (__hip_bfloat16*)w;  w += (size_t)NL * IN_DIM * 2;
    __hip_bfloat16* Btig = (__hip_bfloat16*)w;  w += (size_t)1024 * 1024 * 2;
    __hip_bfloat16* Btc  = (__hip_bfloat16*)w;  w += (size_t)NL * NCONN * 2;
    __hip_bfloat16* ihb  = (__hip_bfloat16*)w;  w += 512 * 2;

    // prep: Btig rows 0..511 = [Wi;Ri]^T, rows 512..1023 = [Wg;Rg]^T
    wconv_transpose<<<32, 256, 0, stream>>>(Wf, WfT, 256, 512, 256, 0);
    wconv_transpose<<<64, 256, 0, stream>>>(Wi, Btig, 512, 512, 1024, 0);
    wconv_transpose<<<64, 256, 0, stream>>>(Ri, Btig, 512, 512, 1024, 512);
    wconv_transpose<<<64, 256, 0, stream>>>(Wg, Btig + (size_t)512 * 1024, 512, 512, 1024, 0);
    wconv_transpose<<<64, 256, 0, stream>>>(Rg, Btig + (size_t)512 * 1024, 512, 512, 1024, 512);
    wconv_transpose<<<32, 256, 0, stream>>>(Wc, Btc, 256, 512, 256, 0);
    fill_ihb<<<1, 512, 0, stream>>>(init_h, ihb);

    // z = LN(cos(x^T Wf + bf)) -> zbuf  (x staged in-kernel)
    k1_mfma_fourier_ln<<<M_TOT / 64, 512, 0, stream>>>(
        x, WfT, bfv, gamma, beta, zbuf);

    // iu = sigmoid([z|zp]@[Wi;Ri]^T + bi) * (conn@Wc + bc)   (512 blocks)
    gates_iu<<<512, 256, 0, stream>>>(zbuf, Btig, conn, Btc, ihb, bi, bc, ubuf);

    // f = sigmoid([z|zp]@[Wg;Rg]^T + bg)                     (512 blocks)
    gates_f<<<512, 256, 0, stream>>>(zbuf, Btig + (size_t)512 * 1024, ihb, bg, fbuf);

    k3_scan<<<NB * 8, 64, 0, stream>>>(zbuf, fbuf, ubuf, init_c, (float*)d_out);
}